// Round 14
// baseline (103.843 us; speedup 1.0000x reference)
//
#include <hip/hip_runtime.h>

typedef __attribute__((ext_vector_type(8))) __bf16  bf16x8;
typedef __attribute__((ext_vector_type(8))) short   short8;
typedef __attribute__((ext_vector_type(4))) float   f32x4;

#define DM   512
#define BM   128
#define BN   128
#define BK   32
#define NNT  4                  // n-tiles (512/128)
#define NKT  16                 // k-tiles (512/32)
#define TILEB 8192              // bytes per tile image (128x32 bf16)
#define NMT  64                 // m-tiles per head (8192/128)
#define G_BYTES   (8 * NNT * NKT * TILEB)            // 4 MiB
#define A_BYTES   (8 * NMT * NKT * TILEB)            // 64 MiB
#define WS_NEED   (G_BYTES + A_BYTES)

// Identity ("fragment-order") tile layout: 8 subtiles of 16 rows; within
// subtile, lane l's 16B slot = row (l&15), k-slot (l>>4).  Every MFMA frag
// read is then  base + lane*16  -> provably zero LDS bank conflicts.
__device__ __forceinline__ int idoff(int r, int s) {   // r in [0,128), s in [0,4)
  return (r >> 4) * 1024 + (((r & 15) + (s << 4)) << 4);
}

__device__ __forceinline__ short f2bf(float f) {
  union { float f; unsigned u; } v; v.f = f;
  unsigned r = v.u + 0x7fffu + ((v.u >> 16) & 1u);   // RNE
  return (short)(r >> 16);
}

// ---- G builder: softmax(taps) + conv folded, written as identity-layout images
__global__ void build_g_kernel(const float* __restrict__ w,
                               const float* __restrict__ fcw,
                               short* __restrict__ Gt) {
  int idx = blockIdx.x * 256 + threadIdx.x;   // 8*512*512/8 threads
  int h  = idx >> 15;
  int t  = idx & 32767;
  int e  = t >> 6;
  int d0 = (t & 63) << 3;
  float w0 = w[h*3+0], w1 = w[h*3+1], w2 = w[h*3+2];
  float mx = fmaxf(w0, fmaxf(w1, w2));
  float e0 = __expf(w0-mx), e1 = __expf(w1-mx), e2 = __expf(w2-mx);
  float inv = 1.0f / (e0 + e1 + e2);
  float w0n = e0*inv, w1n = e1*inv, w2n = e2*inv;
  const float* row = fcw + e * DM;
  float v[10];
  v[0] = (d0 > 0) ? row[d0-1] : 0.0f;
  float4 a = *(const float4*)(row + d0);
  float4 b = *(const float4*)(row + d0 + 4);
  v[1]=a.x; v[2]=a.y; v[3]=a.z; v[4]=a.w;
  v[5]=b.x; v[6]=b.y; v[7]=b.z; v[8]=b.w;
  v[9] = (d0 + 8 < DM) ? row[d0+8] : 0.0f;
  short8 sv;
  #pragma unroll
  for (int j = 0; j < 8; ++j)
    sv[j] = f2bf(w1n*v[j+1] + w0n*v[j+2] + w2n*v[j]);
  int nt = e >> 7, er = e & 127;
  int kt = d0 >> 5, s = (d0 >> 3) & 3;
  char* tile = (char*)Gt + (size_t)((h * NNT + nt) * NKT + kt) * TILEB;
  *(short8*)(tile + idoff(er, s)) = sv;
}

// ---- A builder: x f32 -> bf16 identity-layout tile images (one (h,mt,kt)/block)
__global__ __launch_bounds__(256) void build_a_kernel(const float* __restrict__ x,
                                                      char* __restrict__ Aimg) {
  int bid = blockIdx.x;           // 8*64*16 = 8192 blocks
  int kt = bid & 15;
  int mt = (bid >> 4) & 63;
  int h  = bid >> 10;
  int tid = threadIdx.x;
  char* tile = Aimg + (size_t)bid * TILEB;
  #pragma unroll
  for (int p = 0; p < 2; ++p) {
    int r = (tid >> 2) + 64 * p;
    int s = tid & 3;
    const float* xr = x + (size_t)(h + 8 * (mt * 128 + r)) * DM + kt * BK + s * 8;
    float4 va = *(const float4*)xr;
    float4 vb = *(const float4*)(xr + 4);
    bf16x8 v;
    v[0]=(__bf16)va.x; v[1]=(__bf16)va.y; v[2]=(__bf16)va.z; v[3]=(__bf16)va.w;
    v[4]=(__bf16)vb.x; v[5]=(__bf16)vb.y; v[6]=(__bf16)vb.z; v[7]=(__bf16)vb.w;
    *(bf16x8*)(tile + idoff(r, s)) = v;
  }
}

// ---- Main GEMM: pure gload_lds staging (A+B images), 3-buffer counted-vmcnt
// pipeline, linear ds_read frags, 16 MFMA/iter.
__global__ __launch_bounds__(256, 4) void gemm_img(const char* __restrict__ Aimg,
                                                   const char* __restrict__ Gt,
                                                   float* __restrict__ out) {
  int bid = blockIdx.x;          // 2048 blocks
  int h   = bid & 7;             // head == XCD
  int idx = bid >> 3;
  int nt  = idx & 3;             // nt fastest: co-resident quads share A in L2
  int mt  = idx >> 2;
  int tid  = threadIdx.x;
  int lane = tid & 63;
  int wid  = tid >> 6;
  int wr = wid >> 1, wc = wid & 1;   // 2x2 waves, 64x64 each

  __shared__ char Abuf[3 * TILEB];   // 24 KiB
  __shared__ char Bbuf[3 * TILEB];   // 24 KiB

  const char* Asrc0 = Aimg + (size_t)((h * NMT + mt) * NKT) * TILEB;
  const char* Bsrc0 = Gt + (size_t)((h * NNT + nt) * NKT) * TILEB;

  f32x4 acc[4][4] = {};

#define STAGE(KT, BUF) do {                                                  \
    const char* as_ = Asrc0 + (KT) * TILEB;                                  \
    const char* bs_ = Bsrc0 + (KT) * TILEB;                                  \
    char* ad_ = Abuf + (BUF) * TILEB;                                        \
    char* bd_ = Bbuf + (BUF) * TILEB;                                        \
    _Pragma("unroll")                                                        \
    for (int p = 0; p < 2; ++p) {                                            \
      __builtin_amdgcn_global_load_lds((const void*)(as_ + p*4096 + tid*16), \
                                       (void*)(ad_ + p*4096 + wid*1024), 16, 0, 0); \
      __builtin_amdgcn_global_load_lds((const void*)(bs_ + p*4096 + tid*16), \
                                       (void*)(bd_ + p*4096 + wid*1024), 16, 0, 0); \
    }                                                                        \
  } while (0)

#define COMP(BUF) do {                                                       \
    const char* Ap_ = Abuf + (BUF) * TILEB;                                  \
    const char* Bp_ = Bbuf + (BUF) * TILEB;                                  \
    bf16x8 af[4], bfr[4];                                                    \
    _Pragma("unroll")                                                        \
    for (int m = 0; m < 4; ++m)                                              \
      af[m] = *(const bf16x8*)(Ap_ + (wr*4 + m)*1024 + lane*16);             \
    _Pragma("unroll")                                                        \
    for (int n = 0; n < 4; ++n)                                              \
      bfr[n] = *(const bf16x8*)(Bp_ + (wc*4 + n)*1024 + lane*16);            \
    _Pragma("unroll")                                                        \
    for (int m = 0; m < 4; ++m)                                              \
      _Pragma("unroll")                                                      \
      for (int n = 0; n < 4; ++n)                                            \
        acc[m][n] = __builtin_amdgcn_mfma_f32_16x16x32_bf16(af[m], bfr[n],   \
                                                            acc[m][n], 0,0,0);\
  } while (0)

  // Boundary: per-wave counted vmcnt + barrier.  Every wave issues 4 loads per
  // stage in lockstep, so vmcnt(4) == "my stage(kt+1) done"; barrier then
  // guarantees ALL waves' stage(kt+1) done (m201 pattern).
#define BND4() do { asm volatile("s_waitcnt vmcnt(4)" ::: "memory");         \
    __builtin_amdgcn_sched_barrier(0); __builtin_amdgcn_s_barrier();         \
    __builtin_amdgcn_sched_barrier(0); } while (0)
#define BND0() do { asm volatile("s_waitcnt vmcnt(0)" ::: "memory");         \
    __builtin_amdgcn_sched_barrier(0); __builtin_amdgcn_s_barrier();         \
    __builtin_amdgcn_sched_barrier(0); } while (0)

#define GI(T)  do { STAGE((T)+2, ((T)+2)%3); COMP((T)%3); BND4(); } while (0)

  STAGE(0, 0); STAGE(1, 1);
  BND4();                      // own stage(0) done; stage(1) in flight
  GI(0);  GI(1);  GI(2);  GI(3);  GI(4);  GI(5);  GI(6);
  GI(7);  GI(8);  GI(9);  GI(10); GI(11); GI(12); GI(13);
  COMP(14 % 3); BND0();        // kt=14: no prefetch left; drain stage(15)
  COMP(15 % 3);                // kt=15

#undef GI
#undef BND4
#undef BND0
#undef COMP
#undef STAGE

  // epilogue: C/D col = lane&15, row = (lane>>4)*4 + j
  int ln = lane & 15, sf = lane >> 4;
  int e0 = nt * BN + wc * 64 + ln;
  #pragma unroll
  for (int m = 0; m < 4; ++m) {
    int tq = mt * BM + wr * 64 + m * 16 + (sf << 2);
    #pragma unroll
    for (int j = 0; j < 4; ++j) {
      int R = h + 8 * (tq + j);
      float* orow = out + (size_t)R * DM + e0;
      #pragma unroll
      for (int n = 0; n < 4; ++n)
        orow[n * 16] = acc[m][n][j];
    }
  }
}

// ---- Fallback (ws too small): R9-best structure + identity layout.
__global__ __launch_bounds__(256, 4) void gemm_fb(const float* __restrict__ x,
                                                  const char* __restrict__ Gt,
                                                  float* __restrict__ out) {
  int bid = blockIdx.x;
  int h   = bid & 7;
  int idx = bid >> 3;
  int nt  = idx & 3;
  int mt  = idx >> 2;
  int tid  = threadIdx.x;
  int lane = tid & 63;
  int wid  = tid >> 6;
  int wr = wid >> 1, wc = wid & 1;
  int ln = lane & 15, sf = lane >> 4;

  __shared__ char Abuf[2 * TILEB];
  __shared__ char Bbuf[2 * TILEB];

  const char* Bsrc0 = Gt + (size_t)((h * NNT + nt) * NKT) * TILEB;
  const float* Abase = x + (size_t)(h + 8 * (size_t)mt * BM) * DM;

  float4 ap[4];
  auto loadA = [&](int kt) {
    #pragma unroll
    for (int p = 0; p < 2; ++p) {
      int r = (tid >> 2) + 64 * p;
      const float* xr = Abase + (size_t)r * 8 * DM + kt * BK + (tid & 3) * 8;
      ap[2*p]   = *(const float4*)xr;
      ap[2*p+1] = *(const float4*)(xr + 4);
    }
  };
  auto stageB = [&](int kt, int buf) {
    const char* src = Bsrc0 + kt * TILEB;
    char* dst = Bbuf + buf * TILEB;
    #pragma unroll
    for (int p = 0; p < 2; ++p)
      __builtin_amdgcn_global_load_lds((const void*)(src + p*4096 + tid*16),
                                       (void*)(dst + p*4096 + wid*1024), 16, 0, 0);
  };
  auto writeA = [&](int buf) {
    char* dst = Abuf + buf * TILEB;
    #pragma unroll
    for (int p = 0; p < 2; ++p) {
      int r = (tid >> 2) + 64 * p;
      bf16x8 v;
      v[0]=(__bf16)ap[2*p].x;   v[1]=(__bf16)ap[2*p].y;
      v[2]=(__bf16)ap[2*p].z;   v[3]=(__bf16)ap[2*p].w;
      v[4]=(__bf16)ap[2*p+1].x; v[5]=(__bf16)ap[2*p+1].y;
      v[6]=(__bf16)ap[2*p+1].z; v[7]=(__bf16)ap[2*p+1].w;
      *(bf16x8*)(dst + idoff(r, tid & 3)) = v;
    }
  };

  f32x4 acc[4][4] = {};
  auto computeTile = [&](int cur) {
    const char* Ap = Abuf + cur * TILEB;
    const char* Bp = Bbuf + cur * TILEB;
    bf16x8 af[4], bfr[4];
    #pragma unroll
    for (int m = 0; m < 4; ++m)
      af[m] = *(const bf16x8*)(Ap + (wr*4 + m)*1024 + lane*16);
    #pragma unroll
    for (int n = 0; n < 4; ++n)
      bfr[n] = *(const bf16x8*)(Bp + (wc*4 + n)*1024 + lane*16);
    #pragma unroll
    for (int m = 0; m < 4; ++m)
      #pragma unroll
      for (int n = 0; n < 4; ++n)
        acc[m][n] = __builtin_amdgcn_mfma_f32_16x16x32_bf16(af[m], bfr[n], acc[m][n], 0, 0, 0);
  };

  loadA(0); stageB(0, 0); writeA(0);
  __syncthreads();
  for (int kt = 0; kt < NKT; ++kt) {
    int cur = kt & 1, nxt = cur ^ 1;
    if (kt + 1 < NKT) { loadA(kt + 1); stageB(kt + 1, nxt); }
    computeTile(cur);
    if (kt + 1 < NKT) writeA(nxt);
    __syncthreads();
  }

  int e0 = nt * BN + wc * 64 + ln;
  #pragma unroll
  for (int m = 0; m < 4; ++m) {
    int tq = mt * BM + wr * 64 + m * 16 + (sf << 2);
    #pragma unroll
    for (int j = 0; j < 4; ++j) {
      int R = h + 8 * (tq + j);
      float* orow = out + (size_t)R * DM + e0;
      #pragma unroll
      for (int n = 0; n < 4; ++n)
        orow[n * 16] = acc[m][n][j];
    }
  }
}

extern "C" void kernel_launch(void* const* d_in, const int* in_sizes, int n_in,
                              void* d_out, int out_size, void* d_ws, size_t ws_size,
                              hipStream_t stream) {
  const float* x   = (const float*)d_in[0];
  const float* w   = (const float*)d_in[1];
  const float* fcw = (const float*)d_in[2];
  float* out = (float*)d_out;
  short* Gt  = (short*)d_ws;

  hipLaunchKernelGGL(build_g_kernel, dim3(1024), dim3(256), 0, stream, w, fcw, Gt);

  if (ws_size >= (size_t)WS_NEED) {
    char* Aimg = (char*)d_ws + G_BYTES;
    hipLaunchKernelGGL(build_a_kernel, dim3(8 * NMT * NKT), dim3(256), 0, stream,
                       x, Aimg);
    hipLaunchKernelGGL(gemm_img, dim3(8 * NMT * NNT), dim3(256), 0, stream,
                       Aimg, (const char*)Gt, out);
  } else {
    hipLaunchKernelGGL(gemm_fb, dim3(8 * NMT * NNT), dim3(256), 0, stream,
                       x, (const char*)Gt, out);
  }
}

// Round 15
// 100.748 us; speedup vs baseline: 1.0307x; 1.0307x over previous
//
#include <hip/hip_runtime.h>

typedef __attribute__((ext_vector_type(8))) __bf16  bf16x8;
typedef __attribute__((ext_vector_type(8))) short   short8;
typedef __attribute__((ext_vector_type(4))) float   f32x4;

#define DM   512
#define BM   128
#define BN   128
#define BK   32
#define NNT  4                 // n-tiles (512/128)
#define NKT  16                // k-tiles (512/32)
#define TILEB (BN*BK*2)        // 8 KiB per tile image

__device__ __forceinline__ short f2bf(float f) {
  union { float f; unsigned u; } v; v.f = f;
  unsigned r = v.u + 0x7fffu + ((v.u >> 16) & 1u);   // RNE
  return (short)(r >> 16);
}

// Identity ("fragment-order") layout for a [128 r][32 k] bf16 tile:
// 16B slot for (row r, k-slot s) at (r>>4)*1024 + ((r&15) + 16*s)*16.
// MFMA frag reads become  base + subtile*1024 + lane*16  (linear-in-lane,
// the same pattern global_load_lds writes) -> zero counted LDS conflicts.
__device__ __forceinline__ int idoff(int r, int s) {
  return (r >> 4) * 1024 + (((r & 15) + (s << 4)) << 4);
}

// Fold softmax(taps) + conv into per-head G[h][e][d], stored as
// fragment-order per-(h,nt,kt) 128x32 tile images. 8 d's per thread.
__global__ void build_g_kernel(const float* __restrict__ w,
                               const float* __restrict__ fcw,
                               short* __restrict__ Gt) {
  int idx = blockIdx.x * 256 + threadIdx.x;   // 8*512*512/8 threads
  int h  = idx >> 15;
  int t  = idx & 32767;
  int e  = t >> 6;
  int d0 = (t & 63) << 3;
  float w0 = w[h*3+0], w1 = w[h*3+1], w2 = w[h*3+2];
  float mx = fmaxf(w0, fmaxf(w1, w2));
  float e0 = __expf(w0-mx), e1 = __expf(w1-mx), e2 = __expf(w2-mx);
  float inv = 1.0f / (e0 + e1 + e2);
  float w0n = e0*inv, w1n = e1*inv, w2n = e2*inv;
  const float* row = fcw + e * DM;
  float v[10];
  v[0] = (d0 > 0) ? row[d0-1] : 0.0f;
  float4 a = *(const float4*)(row + d0);
  float4 b = *(const float4*)(row + d0 + 4);
  v[1]=a.x; v[2]=a.y; v[3]=a.z; v[4]=a.w;
  v[5]=b.x; v[6]=b.y; v[7]=b.z; v[8]=b.w;
  v[9] = (d0 + 8 < DM) ? row[d0+8] : 0.0f;
  short8 sv;
  #pragma unroll
  for (int j = 0; j < 8; ++j)
    sv[j] = f2bf(w1n*v[j+1] + w0n*v[j+2] + w2n*v[j]);
  int nt = e >> 7, er = e & 127;
  int kt = d0 >> 5, s = (d0 >> 3) & 3;
  char* tile = (char*)Gt + (size_t)((h * NNT + nt) * NKT + kt) * TILEB;
  *(short8*)(tile + idoff(er, s)) = sv;
}

// y[R,e] = sum_d x[R,d] * G[R%8][e,d]; R = h + 8*t
// R9 structure (4 blocks/CU, 32 KiB LDS, 1-barrier prefetch loop), with the
// identity layout: all ds_write/ds_read at base + tid*16 (0 conflicts).
__global__ __launch_bounds__(256, 4) void gemm_kernel(const float* __restrict__ x,
                                                      const short* __restrict__ Gt,
                                                      float* __restrict__ out) {
  int bid = blockIdx.x;          // 2048 blocks = 8/CU
  int h   = bid & 7;             // head == XCD
  int idx = bid >> 3;
  int nt  = idx & 3;             // nt fastest: co-scheduled nt-quads share A in L2
  int mt  = idx >> 2;            // 64 mtiles
  int tid  = threadIdx.x;
  int lane = tid & 63;
  int wid  = tid >> 6;
  int wr = wid >> 1, wc = wid & 1;   // 2x2 wave grid, 64x64 per wave
  int ln = lane & 15, sf = lane >> 4;

  __shared__ char Alds[2][TILEB];   // 2 x 8 KiB fragment-order
  __shared__ char Blds[2][TILEB];   // 2 x 8 KiB fragment-order

  const char* Bsrc0 = (const char*)Gt + (size_t)(h * NNT + nt) * NKT * TILEB;
  const float* Abase = x + (size_t)(h + 8 * (size_t)mt * BM) * DM;

  float4 ap[4];   // A prefetch regs (16 VGPR)

  // Thread tid's slots: slot = p*256 + tid -> row = (slot>>6)*16 + (slot&15),
  // k-slot s = (slot>>4)&3.  LDS dst is then p*4096 + tid*16 (LINEAR).
  auto loadA = [&](int kt) {
    #pragma unroll
    for (int p = 0; p < 2; ++p) {
      int slot = p * 256 + tid;
      int row  = ((slot >> 6) << 4) + (slot & 15);
      int s    = (slot >> 4) & 3;
      const float* xr = Abase + (size_t)row * 8 * DM + kt * BK + s * 8;
      ap[2*p]   = *(const float4*)xr;
      ap[2*p+1] = *(const float4*)(xr + 4);
    }
  };
  auto stageB = [&](int kt, int buf) {   // 2 x gload_lds dwordx4, linear copy
    const char* src = Bsrc0 + kt * TILEB;
    char* dst = Blds[buf];
    #pragma unroll
    for (int p = 0; p < 2; ++p)
      __builtin_amdgcn_global_load_lds((const void*)(src + p * 4096 + tid * 16),
                                       (void*)(dst + p * 4096 + wid * 1024), 16, 0, 0);
  };
  auto writeA = [&](int buf) {   // linear ds_write_b128 at tid*16
    char* dst = Alds[buf];
    #pragma unroll
    for (int p = 0; p < 2; ++p) {
      short8 v;
      v[0]=f2bf(ap[2*p].x);   v[1]=f2bf(ap[2*p].y);
      v[2]=f2bf(ap[2*p].z);   v[3]=f2bf(ap[2*p].w);
      v[4]=f2bf(ap[2*p+1].x); v[5]=f2bf(ap[2*p+1].y);
      v[6]=f2bf(ap[2*p+1].z); v[7]=f2bf(ap[2*p+1].w);
      *(short8*)(dst + p * 4096 + tid * 16) = v;
    }
  };

  f32x4 acc[4][4] = {};   // wave tile 64x64

  auto computeTile = [&](int cur) {
    const char* Ap = Alds[cur];
    const char* Bp = Blds[cur];
    bf16x8 af[4], bfr[4];
    #pragma unroll
    for (int m = 0; m < 4; ++m)
      af[m] = *(const bf16x8*)(Ap + (wr*4 + m) * 1024 + lane * 16);
    #pragma unroll
    for (int n = 0; n < 4; ++n)
      bfr[n] = *(const bf16x8*)(Bp + (wc*4 + n) * 1024 + lane * 16);
    #pragma unroll
    for (int m = 0; m < 4; ++m)
      #pragma unroll
      for (int n = 0; n < 4; ++n)
        acc[m][n] = __builtin_amdgcn_mfma_f32_16x16x32_bf16(af[m], bfr[n], acc[m][n], 0, 0, 0);
  };

  // prologue: tile 0 -> buf 0
  loadA(0);
  stageB(0, 0);
  writeA(0);
  __syncthreads();

  for (int kt = 0; kt < NKT; ++kt) {
    int cur = kt & 1, nxt = cur ^ 1;
    if (kt + 1 < NKT) {            // issue next tile's loads before compute
      loadA(kt + 1);
      stageB(kt + 1, nxt);
    }
    computeTile(cur);
    if (kt + 1 < NKT) writeA(nxt); // convert + ds_write after compute
    __syncthreads();               // boundary drain
  }

  // epilogue: C/D layout col = lane&15, row = (lane>>4)*4 + j
  int e0 = nt * BN + wc * 64 + ln;
  #pragma unroll
  for (int m = 0; m < 4; ++m) {
    int tq = mt * BM + wr * 64 + m * 16 + (sf << 2);
    #pragma unroll
    for (int j = 0; j < 4; ++j) {
      int R = h + 8 * (tq + j);
      float* orow = out + (size_t)R * DM + e0;
      #pragma unroll
      for (int n = 0; n < 4; ++n)
        orow[n * 16] = acc[m][n][j];
    }
  }
}

extern "C" void kernel_launch(void* const* d_in, const int* in_sizes, int n_in,
                              void* d_out, int out_size, void* d_ws, size_t ws_size,
                              hipStream_t stream) {
  const float* x   = (const float*)d_in[0];
  const float* w   = (const float*)d_in[1];
  const float* fcw = (const float*)d_in[2];
  float* out = (float*)d_out;
  short* Gt  = (short*)d_ws;   // 8*4*16 tiles * 8 KiB = 4 MiB fragment-order

  hipLaunchKernelGGL(build_g_kernel, dim3(1024), dim3(256), 0, stream,
                     w, fcw, Gt);
  hipLaunchKernelGGL(gemm_kernel, dim3(8 * 64 * NNT), dim3(256), 0, stream,
                     x, Gt, out);
}

// Round 16
// 79.251 us; speedup vs baseline: 1.3103x; 1.2712x over previous
//
#include <hip/hip_runtime.h>

typedef __attribute__((ext_vector_type(8))) __bf16  bf16x8;
typedef __attribute__((ext_vector_type(8))) short   short8;
typedef __attribute__((ext_vector_type(4))) float   f32x4;

#define DM   512
#define BM   128
#define BN   128
#define BK   32
#define NNT  4                 // n-tiles (512/128)
#define NKT  16                // k-tiles (512/32)
#define TILEB (BN*BK*2)        // 8 KiB per B tile image

__device__ __forceinline__ short f2bf(float f) {
  union { float f; unsigned u; } v; v.f = f;
  unsigned r = v.u + 0x7fffu + ((v.u >> 16) & 1u);   // RNE
  return (short)(r >> 16);
}

// XOR swizzle within a [rows][32 bf16] tile (64B row stride), 16B granular.
__device__ __forceinline__ int swz(int r, int cbyte) {
  return (r * 64 + cbyte) ^ ((r & 3) << 4);
}

// Fold softmax(taps) + conv into per-head G[h][e][d], stored as pre-swizzled
// per-(h,nt,kt) 128x32 LDS tile images. 8 d's per thread.
__global__ void build_g_kernel(const float* __restrict__ w,
                               const float* __restrict__ fcw,
                               short* __restrict__ Gt) {
  int idx = blockIdx.x * 256 + threadIdx.x;   // 8*512*512/8 threads
  int h  = idx >> 15;
  int t  = idx & 32767;
  int e  = t >> 6;
  int d0 = (t & 63) << 3;
  float w0 = w[h*3+0], w1 = w[h*3+1], w2 = w[h*3+2];
  float mx = fmaxf(w0, fmaxf(w1, w2));
  float e0 = __expf(w0-mx), e1 = __expf(w1-mx), e2 = __expf(w2-mx);
  float inv = 1.0f / (e0 + e1 + e2);
  float w0n = e0*inv, w1n = e1*inv, w2n = e2*inv;
  const float* row = fcw + e * DM;
  float v[10];
  v[0] = (d0 > 0) ? row[d0-1] : 0.0f;
  float4 a = *(const float4*)(row + d0);
  float4 b = *(const float4*)(row + d0 + 4);
  v[1]=a.x; v[2]=a.y; v[3]=a.z; v[4]=a.w;
  v[5]=b.x; v[6]=b.y; v[7]=b.z; v[8]=b.w;
  v[9] = (d0 + 8 < DM) ? row[d0+8] : 0.0f;
  short8 sv;
  #pragma unroll
  for (int j = 0; j < 8; ++j)
    sv[j] = f2bf(w1n*v[j+1] + w0n*v[j+2] + w2n*v[j]);
  int nt = e >> 7, r = e & 127;
  int kt = d0 >> 5, c = d0 & 31;
  char* tile = (char*)Gt + (size_t)((h * NNT + nt) * NKT + kt) * TILEB;
  *(short8*)(tile + swz(r, c * 2)) = sv;
}

// y[R,e] = sum_d x[R,d] * G[R%8][e,d]; R = h + 8*t
// R9 structure (best: 78.8us) + T5 setprio around the MFMA cluster.
// 4 independent blocks/CU at skewed phases = T5's paying regime (m191).
__global__ __launch_bounds__(256, 4) void gemm_kernel(const float* __restrict__ x,
                                                      const short* __restrict__ Gt,
                                                      float* __restrict__ out) {
  int bid = blockIdx.x;          // 2048 blocks = 8/CU
  int h   = bid & 7;             // head == XCD
  int idx = bid >> 3;
  int nt  = idx & 3;             // nt fastest: co-scheduled nt-quads share A in L2
  int mt  = idx >> 2;            // 64 mtiles
  int tid  = threadIdx.x;
  int lane = tid & 63;
  int wid  = tid >> 6;
  int wr = wid >> 1, wc = wid & 1;   // 2x2 wave grid, 64x64 per wave

  __shared__ short Alds[2][BM * BK];   // 2 x 8 KiB swizzled
  __shared__ short Blds[2][BN * BK];   // 2 x 8 KiB swizzled

  const char* Bsrc0 = (const char*)Gt + (size_t)(h * NNT + nt) * NKT * TILEB;
  const float* Abase = x + (size_t)(h + 8 * (size_t)mt * BM) * DM;

  float4 ap[4];   // A prefetch regs (16 VGPR)

  auto loadA = [&](int kt) {
    #pragma unroll
    for (int p = 0; p < 2; ++p) {
      int r = (tid >> 2) + 64 * p;
      const float* xr = Abase + (size_t)r * 8 * DM + kt * BK + (tid & 3) * 8;
      ap[2*p]   = *(const float4*)xr;
      ap[2*p+1] = *(const float4*)(xr + 4);
    }
  };
  auto stageB = [&](int kt, int buf) {   // 2 x gload_lds dwordx4 per thread
    const char* src = Bsrc0 + kt * TILEB;
    char* dst = (char*)Blds[buf];
    #pragma unroll
    for (int p = 0; p < 2; ++p)
      __builtin_amdgcn_global_load_lds((const void*)(src + p * 4096 + tid * 16),
                                       (void*)(dst + p * 4096 + wid * 1024), 16, 0, 0);
  };
  auto writeA = [&](int buf) {
    char* dst = (char*)Alds[buf];
    #pragma unroll
    for (int p = 0; p < 2; ++p) {
      int r = (tid >> 2) + 64 * p;
      short8 sv;
      sv[0]=f2bf(ap[2*p].x);   sv[1]=f2bf(ap[2*p].y);
      sv[2]=f2bf(ap[2*p].z);   sv[3]=f2bf(ap[2*p].w);
      sv[4]=f2bf(ap[2*p+1].x); sv[5]=f2bf(ap[2*p+1].y);
      sv[6]=f2bf(ap[2*p+1].z); sv[7]=f2bf(ap[2*p+1].w);
      *(short8*)(dst + swz(r, (tid & 3) * 16)) = sv;
    }
  };

  f32x4 acc[4][4] = {};   // wave tile 64x64

  auto computeTile = [&](int cur) {
    const char* Ap = (const char*)Alds[cur];
    const char* Bp = (const char*)Blds[cur];
    bf16x8 af[4], bfr[4];
    #pragma unroll
    for (int m = 0; m < 4; ++m)
      af[m] = *(const bf16x8*)(Ap + swz(wr*64 + m*16 + (lane & 15),
                                        (lane >> 4) * 16));
    #pragma unroll
    for (int n = 0; n < 4; ++n)
      bfr[n] = *(const bf16x8*)(Bp + swz(wc*64 + n*16 + (lane & 15),
                                         (lane >> 4) * 16));
    __builtin_amdgcn_s_setprio(1);          // T5: favor the MFMA-entering wave
    #pragma unroll
    for (int m = 0; m < 4; ++m)
      #pragma unroll
      for (int n = 0; n < 4; ++n)
        acc[m][n] = __builtin_amdgcn_mfma_f32_16x16x32_bf16(af[m], bfr[n], acc[m][n], 0, 0, 0);
    __builtin_amdgcn_s_setprio(0);
  };

  // prologue: tile 0 -> buf 0
  loadA(0);
  stageB(0, 0);
  writeA(0);
  __syncthreads();

  for (int kt = 0; kt < NKT; ++kt) {
    int cur = kt & 1, nxt = cur ^ 1;
    if (kt + 1 < NKT) {            // issue next tile's loads before compute
      loadA(kt + 1);
      stageB(kt + 1, nxt);
    }
    computeTile(cur);
    if (kt + 1 < NKT) writeA(nxt); // convert + ds_write after compute
    __syncthreads();               // boundary drain
  }

  // epilogue: C/D layout col = lane&15, row = (lane>>4)*4 + j
  int e0 = nt * BN + wc * 64 + (lane & 15);
  #pragma unroll
  for (int m = 0; m < 4; ++m) {
    int tq = mt * BM + wr * 64 + m * 16 + ((lane >> 4) << 2);
    #pragma unroll
    for (int j = 0; j < 4; ++j) {
      int R = h + 8 * (tq + j);
      float* orow = out + (size_t)R * DM + e0;
      #pragma unroll
      for (int n = 0; n < 4; ++n)
        orow[n * 16] = acc[m][n][j];
    }
  }
}

extern "C" void kernel_launch(void* const* d_in, const int* in_sizes, int n_in,
                              void* d_out, int out_size, void* d_ws, size_t ws_size,
                              hipStream_t stream) {
  const float* x   = (const float*)d_in[0];
  const float* w   = (const float*)d_in[1];
  const float* fcw = (const float*)d_in[2];
  float* out = (float*)d_out;
  short* Gt  = (short*)d_ws;   // 8*4*16 tiles * 8 KiB = 4 MiB pre-swizzled

  hipLaunchKernelGGL(build_g_kernel, dim3((8 * DM * DM / 8) / 256), dim3(256), 0, stream,
                     w, fcw, Gt);
  hipLaunchKernelGGL(gemm_kernel, dim3(8 * 64 * NNT), dim3(256), 0, stream,
                     x, Gt, out);
}